// Round 5
// baseline (240.144 us; speedup 1.0000x reference)
//
#include <hip/hip_runtime.h>

// MS-SSIM loss, 5 levels.
// R15: amortize fixed costs. Post-mortem R14: l0 124us (pool fusion +
//   XCD swizzle: FETCH 185->56MB, win); BUT merged lvls ~105us ~= R13's
//   five serialized dispatches -> DISCRIMINATOR: per-subtile-generation
//   cost is invariant to dispatch structure (occ pinned ~17%, VALUBusy
//   29%). lvls block = 42-row prologue + 1-2 subtiles: ~70% fixed cost,
//   paid 2544x. Also R14 regression: pool_tree load+consume same phase
//   (exposed round trips, wave1 idle). Fixes:
//   (a) full-height strips: L0 NSUB=8 (1536 blk), lvls L1 NSUB=8/384,
//       L2 4/192, L3 2/96, L4 1/48 = 720 blk -> tail prologue work -60%,
//       generations 3.7 -> ~1.4.
//   (b) pool split load-early/finish-late AND across waves (wave0=x,
//       wave1=y, 4 float4/lane, per-wave shfl tree).
//   (c) no XCD swizzle for lvls (heterogeneous durations -> chunked
//       swizzle piles all L1 on XCDs 0-3; natural order interleaves).
//   Watch: WRITE_SIZE ~48MB (spill tripwire), VGPR ~135-155.
//   If l0 flat + occ ~17% again -> next: raw-tile LDS staging via
//   global_load_lds (kills 3x horizontal read amplification).
// Carried (counter-verified): channel-packed (hx,hy,hxx+hyy,hxy) v4f
// window, XOR swizzle; rolling 42-row window, 32 new rows/subtile;
// prefetch a full V-phase ahead; TW=32/128thr (21.5KB LDS); spread
// atomics; padded pyramid + zpad row-select; fastp edge path.

#define TW 32
#define NTHR 128
#define NIMG 48
#define WIN 42                 // rolling window rows (32 + 10)
#define PQ  32                 // v4f pitch, packed channels, XOR-swizzled
#define NSLOT 256
#define SSTRIDE 16             // 64 B between slots -> 1 cache line each

// padded pyramid geometry (8 zero cols each side)
#define RS1 272
#define RS2 144
#define RS3 80
#define RS4 48
#define IS0 (512L*512)
#define IS1 (256L*272)
#define IS2 (128L*144)
#define IS3 (64L*80)
#define IS4 (32L*48)

typedef float v4f __attribute__((ext_vector_type(4)));

struct Pyr {
    float *x1, *y1, *x2, *y2, *x3, *y3, *x4, *y4;
};

__device__ __forceinline__ void h_load(
    const float* __restrict__ xi, const float* __restrict__ yi,
    const float* __restrict__ zpad, int gr, int gc0, int H, int W,
    bool fastp, int rowStride, float* xv, float* yv)
{
    const bool rok = ((unsigned)gr < (unsigned)H);
    if (fastp) {
        const float* px = rok ? (xi + (long)gr * rowStride + gc0) : zpad;
        const float* py = rok ? (yi + (long)gr * rowStride + gc0) : zpad;
#pragma unroll
        for (int v = 0; v < 6; ++v) {
            const float4 a = reinterpret_cast<const float4*>(px)[v];
            const float4 b = reinterpret_cast<const float4*>(py)[v];
            xv[4*v+0]=a.x; xv[4*v+1]=a.y; xv[4*v+2]=a.z; xv[4*v+3]=a.w;
            yv[4*v+0]=b.x; yv[4*v+1]=b.y; yv[4*v+2]=b.z; yv[4*v+3]=b.w;
        }
    } else {
        const float* xrow = xi + (long)gr * rowStride;
        const float* yrow = yi + (long)gr * rowStride;
#pragma unroll
        for (int k = 3; k < 21; ++k) {
            const int gc = gc0 + k;
            const bool ok = rok && ((unsigned)gc < (unsigned)W);
            xv[k] = ok ? xrow[gc] : 0.0f;
            yv[k] = ok ? yrow[gc] : 0.0f;
        }
    }
}

// H-conv 8 output cols, packed channels (x, y, x^2+y^2, xy) -> one b128/col
__device__ __forceinline__ void h_conv_write(
    const float* xv, const float* yv, v4f* smA, int slot, int cb,
    const float* G)
{
    v4f s[8];
#pragma unroll
    for (int j = 0; j < 8; ++j) s[j] = {0.f, 0.f, 0.f, 0.f};
#pragma unroll
    for (int m = 0; m < 18; ++m) {
        const float a = xv[m+3], b = yv[m+3];
        v4f w; w.x = a; w.y = b; w.z = a*a + b*b; w.w = a*b;
#pragma unroll
        for (int j = 0; j < 8; ++j) {
            if (j <= m && m - j <= 10) {
                s[j] += w * G[m - j];              // 2x v_pk_fma_f32
            }
        }
    }
    const int u = slot & 31;
#pragma unroll
    for (int j = 0; j < 8; ++j)
        smA[slot * PQ + ((cb + j) ^ u)] = s[j];    // ds_write_b128
}

// V-conv 8 output rows at col c + SSIM epilogue; returns partial sum
__device__ __forceinline__ float v_phase(
    const v4f* smA, int vb, int c, int rr0, int R0, int C0, int H, int W,
    const float* G)
{
    const float C1 = 4.0e-4f;
    const float C2 = 3.6e-3f;
    v4f acc[8];
#pragma unroll
    for (int i = 0; i < 8; ++i) acc[i] = {0.f, 0.f, 0.f, 0.f};
    int sl = vb;
#pragma unroll
    for (int k = 0; k < 18; ++k) {
        const v4f h = smA[sl * PQ + (c ^ (sl & 31))];  // ds_read_b128
#pragma unroll
        for (int i = 0; i < 8; ++i) {
            if (i <= k && k - i <= 10) {
                acc[i] += h * G[k - i];            // 2x v_pk_fma_f32
            }
        }
        sl = (sl + 1 == WIN) ? 0 : sl + 1;
    }
    float local = 0.f;
    const int gc = C0 + c;
#pragma unroll
    for (int i = 0; i < 8; ++i) {
        const int gr2 = R0 + rr0 + i;
        if (gr2 < H && gc < W) {
            const float mu1 = acc[i].x, mu2 = acc[i].y;
            const float mu1s = mu1*mu1, mu2s = mu2*mu2, m12 = mu1*mu2;
            const float ssum = acc[i].z - mu1s - mu2s;   // sig1+sig2
            const float s12  = acc[i].w - m12;
            const float num = (2.f * m12 + C1) * (2.f * s12 + C2);
            const float den = (mu1s + mu2s + C1) * (ssum + C2);
            local += num * __builtin_amdgcn_rcpf(den + 1e-8f);
        }
    }
    return local;
}

// ---- pool, split into load (issue early) and finish (consume late). ----
// Each wave handles ONE image: wave0 -> x, wave1 -> y. Lane (r,c2) owns a
// 4x4 input patch of the 32x32 subtile; shfl tree builds levels 2-4.
__device__ __forceinline__ void pool_load(
    const float* __restrict__ pi, int lane, int R0, int C0, float4* a)
{
    const int r = lane >> 3, c2 = lane & 7;
    const float* s = pi + (long)(R0 + 4*r) * 512 + (C0 + 4*c2);
#pragma unroll
    for (int rr = 0; rr < 4; ++rr)
        a[rr] = *reinterpret_cast<const float4*>(s + (long)rr * 512);
}

__device__ __forceinline__ void pool_finish(
    const float4* a, int lane, int R0, int C0, int bx,
    float* p1, float* p2, float* p3, float* p4)
{
    const int r = lane >> 3, c2 = lane & 7;
    const float q00 = 0.25f*(a[0].x+a[0].y+a[1].x+a[1].y);
    const float q01 = 0.25f*(a[0].z+a[0].w+a[1].z+a[1].w);
    const float q10 = 0.25f*(a[2].x+a[2].y+a[3].x+a[3].y);
    const float q11 = 0.25f*(a[2].z+a[2].w+a[3].z+a[3].w);
    const int r1 = (R0 >> 1) + 2*r, c1 = (C0 >> 1) + 2*c2;
    *reinterpret_cast<float2*>(p1 + (long)r1*RS1 + c1) = make_float2(q00, q01);
    *reinterpret_cast<float2*>(p1 + (long)(r1+1)*RS1 + c1) = make_float2(q10, q11);
    const float v2 = 0.25f*(q00+q01+q10+q11);
    p2[(long)((R0>>2)+r)*RS2 + (C0>>2)+c2] = v2;
    const float v3 = 0.25f*(v2 + __shfl_down(v2,1,64)
                          + __shfl_down(v2,8,64) + __shfl_down(v2,9,64));
    if (!(r & 1) && !(c2 & 1))
        p3[(long)((R0>>3)+(r>>1))*RS3 + (C0>>3)+(c2>>1)] = v3;
    const float v4 = 0.25f*(v3 + __shfl_down(v3,2,64)
                          + __shfl_down(v3,16,64) + __shfl_down(v3,18,64));
    if (!(r & 3) && !(c2 & 3))
        p4[(long)((R0>>4)+(r>>2))*RS4 + (C0>>4)+(c2>>2)] = v4;
    if (bx == 0) {
        p1[(long)r1*RS1 + (c2-8)] = 0.f;
        p1[(long)(r1+1)*RS1 + (c2-8)] = 0.f;
        p2[(long)((R0>>2)+r)*RS2 + (c2-8)] = 0.f;
        if (r < 4) p3[(long)((R0>>3)+r)*RS3 + (c2-8)] = 0.f;
        if (r < 2) p4[(long)((R0>>4)+r)*RS4 + (c2-8)] = 0.f;
    }
    if (bx == 15) {
        p1[(long)r1*RS1 + 256 + c2] = 0.f;
        p1[(long)(r1+1)*RS1 + 256 + c2] = 0.f;
        p2[(long)((R0>>2)+r)*RS2 + 128 + c2] = 0.f;
        if (r < 4) p3[(long)((R0>>3)+r)*RS3 + 64 + c2] = 0.f;
        if (r < 2) p4[(long)((R0>>4)+r)*RS4 + 32 + c2] = 0.f;
    }
}

// ---- level 0: SSIM + full pyramid build. 1536 blocks x 128 thr ----
// Strip = 32 cols x 256 rows (NSUB=8).
__global__ __launch_bounds__(NTHR, 2) void ssim_l0_kernel(
    const float* __restrict__ x, const float* __restrict__ y,
    Pyr p, const float* __restrict__ zpad, float* __restrict__ slots)
{
    const float G[11] = {
        0.00102839f, 0.00759877f, 0.03600077f, 0.10936069f, 0.21300539f,
        0.26601173f, 0.21300539f, 0.10936069f, 0.03600077f, 0.00759877f,
        0.00102839f};

    __shared__ __align__(16) v4f smA[WIN * PQ];   // 21504 B

    const int t    = threadIdx.x;
    const int bid  = blockIdx.x;
    const int tile = (bid & 7) * 192 + (bid >> 3);     // XCD-contiguous
    const int bx   = tile & 15;
    const int by   = (tile >> 4) & 1;
    const int z    = tile >> 5;
    const int C0   = bx * TW;
    const int S0   = by * 256;
    const float* xi = x + (long)z * IS0;
    const float* yi = y + (long)z * IS0;
    const bool fastp = (C0 >= 8) && (C0 + TW + 8 <= 512);

    // per-wave image selection for pool (wave-uniform)
    const int lane = t & 63;
    const float* pimg = (t < 64) ? xi : yi;
    float* q1 = ((t < 64) ? p.x1 : p.y1) + (long)z * IS1;
    float* q2 = ((t < 64) ? p.x2 : p.y2) + (long)z * IS2;
    float* q3 = ((t < 64) ? p.x3 : p.y3) + (long)z * IS3;
    float* q4 = ((t < 64) ? p.x4 : p.y4) + (long)z * IS4;

    // prologue: window rows [S0-5, S0+37)
    for (int s = t; s < WIN * 4; s += NTHR) {
        const int r = s % WIN, q = s / WIN;
        float pxv[24], pyv[24];
        h_load(xi, yi, zpad, S0 + r - 5, C0 + (q << 3) - 8, 512, 512, fastp,
               512, pxv, pyv);
        h_conv_write(pxv, pyv, smA, r, q << 3, G);
    }
    __syncthreads();

    const int c    = t & 31;
    const int rr0  = (t >> 5) * 8;
    const int hr   = t & 31, hq = t >> 5;
    const int hgc0 = C0 + (hq << 3) - 8;
    int wslot = hr, vb = rr0;
    float local = 0.f;

#pragma unroll 1
    for (int tt = 0; tt < 7; ++tt) {
        const int R0 = S0 + 32 * tt;
        // (A) prefetch: next window rows + this subtile's pool rows
        float xv[24], yv[24];
        h_load(xi, yi, zpad, R0 + 37 + hr, hgc0, 512, 512, fastp, 512, xv, yv);
        float4 pa[4];
        pool_load(pimg, lane, R0, C0, pa);
        // (C) V phase covers the loads
        local += v_phase(smA, vb, c, rr0, R0, C0, 512, 512, G);
        __syncthreads();   // all V reads done; prefetched loads landed
        // (D) window update + pool finish
        h_conv_write(xv, yv, smA, wslot, hq << 3, G);
        pool_finish(pa, lane, R0, C0, bx, q1, q2, q3, q4);
        __syncthreads();   // new window rows visible
        wslot += 32; if (wslot >= WIN) wslot -= WIN;
        vb    += 32; if (vb    >= WIN) vb    -= WIN;
    }
    {   // peeled tail subtile
        const int R0 = S0 + 224;
        float4 pa[4];
        pool_load(pimg, lane, R0, C0, pa);
        local += v_phase(smA, vb, c, rr0, R0, C0, 512, 512, G);
        pool_finish(pa, lane, R0, C0, bx, q1, q2, q3, q4);
    }

#pragma unroll
    for (int off = 32; off > 0; off >>= 1) local += __shfl_down(local, off, 64);
    if ((t & 63) == 0) {
        const int slot = ((tile << 1) | (t >> 6)) & (NSLOT - 1);
        atomicAdd(slots + slot * SSTRIDE, local);
    }
}

// ---- levels 1-4 merged, full-height strips:
// L1: 8bx*48 = 384 (NSUB=8), L2: 4bx*48 = 192 (NSUB=4),
// L3: 2bx*48 = 96 (NSUB=2), L4: 48 (NSUB=1). Total 720 blocks.
__global__ __launch_bounds__(NTHR, 2) void ssim_lvls_kernel(
    Pyr p, const float* __restrict__ zpad, float* __restrict__ slots)
{
    const float G[11] = {
        0.00102839f, 0.00759877f, 0.03600077f, 0.10936069f, 0.21300539f,
        0.26601173f, 0.21300539f, 0.10936069f, 0.03600077f, 0.00759877f,
        0.00102839f};

    __shared__ __align__(16) v4f smA[WIN * PQ];

    const int t    = threadIdx.x;
    const int tile = blockIdx.x;        // natural order: levels interleave XCDs

    const float* xi; const float* yi;
    int rowStride, H, C0, nsub, lvl, rem;
    if (tile < 384) {
        rem = tile; lvl = 1; nsub = 8;
        const int bx = rem & 7, z = rem >> 3;
        xi = p.x1 + (long)z * IS1; yi = p.y1 + (long)z * IS1;
        rowStride = RS1; H = 256; C0 = bx * TW;
    } else if (tile < 576) {
        rem = tile - 384; lvl = 2; nsub = 4;
        const int bx = rem & 3, z = rem >> 2;
        xi = p.x2 + (long)z * IS2; yi = p.y2 + (long)z * IS2;
        rowStride = RS2; H = 128; C0 = bx * TW;
    } else if (tile < 672) {
        rem = tile - 576; lvl = 3; nsub = 2;
        const int bx = rem & 1, z = rem >> 1;
        xi = p.x3 + (long)z * IS3; yi = p.y3 + (long)z * IS3;
        rowStride = RS3; H = 64; C0 = bx * TW;
    } else {
        rem = tile - 672; lvl = 4; nsub = 1;
        const int z = rem;
        xi = p.x4 + (long)z * IS4; yi = p.y4 + (long)z * IS4;
        rowStride = RS4; H = 32; C0 = 0;
    }

    // prologue (pad=1 -> fastp always); strips start at row 0
    for (int s = t; s < WIN * 4; s += NTHR) {
        const int r = s % WIN, q = s / WIN;
        float pxv[24], pyv[24];
        h_load(xi, yi, zpad, r - 5, C0 + (q << 3) - 8, H, H, true,
               rowStride, pxv, pyv);
        h_conv_write(pxv, pyv, smA, r, q << 3, G);
    }
    __syncthreads();

    const int c    = t & 31;
    const int rr0  = (t >> 5) * 8;
    const int hr   = t & 31, hq = t >> 5;
    int wslot = hr, vb = rr0;
    float local = 0.f;

#pragma unroll 1
    for (int tt = 0; tt + 1 < nsub; ++tt) {
        const int R0 = 32 * tt;
        float xv[24], yv[24];
        h_load(xi, yi, zpad, R0 + 37 + hr, C0 + (hq << 3) - 8, H, H, true,
               rowStride, xv, yv);
        local += v_phase(smA, vb, c, rr0, R0, C0, H, H, G);
        __syncthreads();
        h_conv_write(xv, yv, smA, wslot, hq << 3, G);
        __syncthreads();
        wslot += 32; if (wslot >= WIN) wslot -= WIN;
        vb    += 32; if (vb    >= WIN) vb    -= WIN;
    }
    local += v_phase(smA, vb, c, rr0, 32 * (nsub - 1), C0, H, H, G);

#pragma unroll
    for (int off = 32; off > 0; off >>= 1) local += __shfl_down(local, off, 64);
    if ((t & 63) == 0) {
        const int slot = ((rem << 1) | (t >> 6)) & (NSLOT - 1);
        atomicAdd(slots + ((long)lvl * NSLOT + slot) * SSTRIDE, local);
    }
}

__global__ void finalize_kernel(const float* __restrict__ slots,
                                float* __restrict__ out)
{
    const int t = threadIdx.x;
    const float w[5] = {0.0448f, 0.2856f, 0.3001f, 0.2363f, 0.1333f};
    const float wsum = w[0] + w[1] + w[2] + w[3] + w[4];
    float acc = 0.f;
#pragma unroll
    for (int lvl = 0; lvl < 5; ++lvl) {
        const int d = 512 >> lvl;
        const float cnt = (float)NIMG * (float)d * (float)d;
        acc += (w[lvl] / wsum) / cnt * slots[(lvl * NSLOT + t) * SSTRIDE];
    }
#pragma unroll
    for (int off = 32; off > 0; off >>= 1) acc += __shfl_down(acc, off, 64);
    __shared__ float pp[4];
    if ((t & 63) == 0) pp[t >> 6] = acc;
    __syncthreads();
    if (t == 0) out[0] = 1.0f - (pp[0] + pp[1] + pp[2] + pp[3]);
}

extern "C" void kernel_launch(void* const* d_in, const int* in_sizes, int n_in,
                              void* d_out, int out_size, void* d_ws, size_t ws_size,
                              hipStream_t stream)
{
    const float* pred = (const float*)d_in[0];
    const float* targ = (const float*)d_in[1];
    float* out = (float*)d_out;
    float* ws  = (float*)d_ws;

    float* slots = ws;                           // 5 * 256 * 16 floats (80 KB)
    float* zpad  = slots + 5 * NSLOT * SSTRIDE;  // 640 zero floats

    Pyr p;
    {
        float* b = zpad + 640;
        p.x1 = b + 8;                 b += NIMG * IS1;
        p.y1 = b + 8;                 b += NIMG * IS1;
        p.x2 = b + 8;                 b += NIMG * IS2;
        p.y2 = b + 8;                 b += NIMG * IS2;
        p.x3 = b + 8;                 b += NIMG * IS3;
        p.y3 = b + 8;                 b += NIMG * IS3;
        p.x4 = b + 8;                 b += NIMG * IS4;
        p.y4 = b + 8;
    }

    hipMemsetAsync(ws, 0, (size_t)(5 * NSLOT * SSTRIDE + 640) * sizeof(float),
                   stream);

    // L0: SSIM + full pyramid. 1536 blocks (32x256 strips).
    ssim_l0_kernel<<<dim3(1536), NTHR, 0, stream>>>(pred, targ, p, zpad, slots);
    // L1-4 merged: 720 full-height strips.
    ssim_lvls_kernel<<<dim3(720), NTHR, 0, stream>>>(p, zpad, slots);

    finalize_kernel<<<1, 256, 0, stream>>>(slots, out);
}